// Round 5
// baseline (78.561 us; speedup 1.0000x reference)
//
#include <hip/hip_runtime.h>

#define B_    32
#define CIN_  64
#define COUT_ 64
#define IMG_  128
#define W4_   32                 // float4 per row
#define PIX4_ 4096               // float4 per plane
#define NPOS_ (B_ * PIX4_)       // 131072 float4 positions

// ---- Kernel A: 2-group partial channel sums. Thread owns 2 positions
// (block covers 8 KiB contiguous per channel); unroll-8 channel walk keeps
// ~16 float4 loads in flight. Reads 134 MB, writes 8 MB of partials. ----
__global__ __launch_bounds__(256) void ch_sum2(const float* __restrict__ x,
                                               float* __restrict__ part) {
    const int g    = blockIdx.y;                    // 0..1 channel group
    const int tid  = threadIdx.x;
    const int i0   = blockIdx.x * 512 + tid;        // chunk of 512 float4
    const int i1   = i0 + 256;                      // same plane (512 | 4096)
    const int b    = i0 >> 12;
    const int p0   = i0 & (PIX4_ - 1);

    const float4* xp = reinterpret_cast<const float4*>(x)
                     + ((size_t)b * CIN_ + (size_t)g * 32) * PIX4_ + p0;

    float4 a0 = make_float4(0.f, 0.f, 0.f, 0.f);
    float4 a1 = make_float4(0.f, 0.f, 0.f, 0.f);
#pragma unroll 8
    for (int c = 0; c < 32; ++c) {
        float4 v0 = xp[(size_t)c * PIX4_];
        float4 v1 = xp[(size_t)c * PIX4_ + 256];
        a0.x += v0.x; a0.y += v0.y; a0.z += v0.z; a0.w += v0.w;
        a1.x += v1.x; a1.y += v1.y; a1.z += v1.z; a1.w += v1.w;
    }
    float4* pp = reinterpret_cast<float4*>(part) + (size_t)g * NPOS_;
    pp[i0] = a0;
    pp[i1] = a1;
}

// ---- Kernel B: each thread owns (b,h,w4); sums the 3x6 stencil from both
// partial planes (L2-resident), computes 32 couts (blockIdx.y group) in
// registers, streams float4 stores. Store-bound; 1024 blocks = 50% occ. ----
__global__ __launch_bounds__(256) void conv_couts(const float* __restrict__ ws,
                                                  const float* __restrict__ kern,
                                                  const float* __restrict__ bias,
                                                  float* __restrict__ out) {
    const int cg = blockIdx.y;                     // 0..1 cout group
    int i = blockIdx.x * 256 + threadIdx.x;        // 0..NPOS_-1
    int b   = i >> 12;
    int rem = i & (PIX4_ - 1);
    int h   = rem >> 5;
    int w4  = rem & 31;

    float v[3][6];
#pragma unroll
    for (int r = 0; r < 3; ++r)
#pragma unroll
        for (int j = 0; j < 6; ++j) v[r][j] = 0.f;

#pragma unroll
    for (int gidx = 0; gidx < 2; ++gidx) {
        const float* base = ws + (size_t)gidx * (NPOS_ * 4) + (size_t)b * IMG_ * IMG_;
#pragma unroll
        for (int dr = -1; dr <= 1; ++dr) {
            const int r = h + dr;
            if (r < 0 || r >= IMG_) continue;
            const float* rp = base + r * IMG_ + w4 * 4;
            float4 c = *reinterpret_cast<const float4*>(rp);
            v[dr + 1][1] += c.x; v[dr + 1][2] += c.y;
            v[dr + 1][3] += c.z; v[dr + 1][4] += c.w;
            if (w4 > 0)  v[dr + 1][0] += rp[-1];
            if (w4 < 31) v[dr + 1][5] += rp[4];
        }
    }

    float4* outp = reinterpret_cast<float4*>(out)
                 + (size_t)b * COUT_ * PIX4_ + (size_t)h * W4_ + w4;

#pragma unroll 4
    for (int j = 0; j < 32; ++j) {
        const int co = cg * 32 + j;
        const float* kw = kern + co * 9;
        const float k0 = kw[0], k1 = kw[1], k2 = kw[2];
        const float k3 = kw[3], k4 = kw[4], k5 = kw[5];
        const float k6 = kw[6], k7 = kw[7], k8 = kw[8];
        const float bv = (float)CIN_ * bias[co];

        float a[4];
#pragma unroll
        for (int q = 0; q < 4; ++q) {
            a[q] = bv
                 + k0 * v[0][q] + k1 * v[0][q + 1] + k2 * v[0][q + 2]
                 + k3 * v[1][q] + k4 * v[1][q + 1] + k5 * v[1][q + 2]
                 + k6 * v[2][q] + k7 * v[2][q + 1] + k8 * v[2][q + 2];
        }
        outp[(size_t)co * PIX4_] = make_float4(a[0], a[1], a[2], a[3]);
    }
}

extern "C" void kernel_launch(void* const* d_in, const int* in_sizes, int n_in,
                              void* d_out, int out_size, void* d_ws, size_t ws_size,
                              hipStream_t stream) {
    const float* x    = (const float*)d_in[0];   // (32,64,128,128) f32
    const float* kern = (const float*)d_in[1];   // (64,3,3) f32
    const float* bias = (const float*)d_in[2];   // (64,1,1,1) f32
    float* out  = (float*)d_out;                 // (32,64,128,128) f32
    float* part = (float*)d_ws;                  // 2 x 2 MiB partials

    dim3 ga(NPOS_ / 512, 2);                     // (256, 2) = 512 blocks
    ch_sum2<<<ga, 256, 0, stream>>>(x, part);

    dim3 gb(NPOS_ / 256, 2);                     // (512, 2) = 1024 blocks
    conv_couts<<<gb, 256, 0, stream>>>(part, kern, bias, out);
}